// Round 10
// baseline (205.036 us; speedup 1.0000x reference)
//
#include <hip/hip_runtime.h>
#include <math.h>

#define NQ    12
#define DIM   4096        // 2^NQ
#define K_EXT 8192        // [hi | lo] extended row
#define NSAMP 2048
#define NLAY  3
#define NT    32          // 2048/64 tiles per dimension
#define NTRI  528         // NT*(NT+1)/2 triangular blocks
#define BK    64
#define LDK   72          // LDS row stride (ushort); 144 B, 16B-aligned rows

typedef __attribute__((ext_vector_type(8)))  short bf16x8;   // 8 bf16 = 4 VGPRs
typedef __attribute__((ext_vector_type(16))) float floatx16; // MFMA 32x32 acc

__device__ __forceinline__ unsigned short f32_to_bf16(float x) {
    unsigned u = __builtin_bit_cast(unsigned, x);
    u += 0x7FFFu + ((u >> 16) & 1u);            // round-to-nearest-even
    return (unsigned short)(u >> 16);
}
__device__ __forceinline__ float bf16_to_f32(unsigned short h) {
    unsigned u = (unsigned)h << 16;
    return __builtin_bit_cast(float, u);
}

// ---------------------------------------------------------------------------
// Kernel 1: one SAMPLE PER WAVE, state in registers (64 amps/lane).
// Amp index i = reg*64 + lane: bits 0-5 = lane (shfl gates), bits 6-11 = reg.
// COMPACT version: layer & lane-qubit loops are runtime (#pragma unroll 1) —
// R9's fully-unrolled variant was ~130 KB of code (4x the 32 KB L1I) and
// I-cache-thrashed at ~85 us.  Only loops indexing v[] stay unrolled.
// CZ parity: popc(i & ror1(i)) = P_lane(lane) ^ P_reg(r) ^ (l5&r0) ^ (l0&r5).
// Emits psi = hi + lo as one extended bf16 row [hi(4096) | lo(4096)].
// ---------------------------------------------------------------------------
__global__ __launch_bounds__(256) void sim_kernel(const float* __restrict__ data,
                                                  const float* __restrict__ params,
                                                  unsigned short* __restrict__ pe)
{
    __shared__ float CS[4*36], SN[4*36];
    const int tid  = threadIdx.x;
    const int wave = tid >> 6, lane = tid & 63;
    const int smp  = blockIdx.x * 4 + wave;

    if (lane < NLAY*NQ) {
        const int q = lane % NQ;
        const float th = 0.5f * (params[lane] + data[smp*NQ + q]);
        CS[wave*36 + lane] = cosf(th);
        SN[wave*36 + lane] = sinf(th);
    }
    __syncthreads();

    float v[64];
    #pragma unroll
    for (int r = 0; r < 64; ++r) v[r] = 0.f;
    if (lane == 0) v[0] = 1.f;

    const int pl = __popc(lane & (lane >> 1) & 0x1F) & 1;
    const int l0 = lane & 1, l5 = (lane >> 5) & 1;
    const float f00 = pl ? -1.f : 1.f;
    const float f10 = (pl ^ l5) ? -1.f : 1.f;
    const float f01 = (pl ^ l0) ? -1.f : 1.f;
    const float f11 = (pl ^ l5 ^ l0) ? -1.f : 1.f;

    #pragma unroll 1
    for (int l = 0; l < NLAY; ++l) {
        const float* cs = &CS[wave*36 + l*NQ];
        const float* sn = &SN[wave*36 + l*NQ];
        // qubits 0-5 (lane bits): runtime q loop, runtime shfl mask
        #pragma unroll 1
        for (int q = 0; q < 6; ++q) {
            const float c = cs[q], s = sn[q];
            const float t = ((lane >> q) & 1) ? s : -s;
            const int   m = 1 << q;
            #pragma unroll
            for (int r = 0; r < 64; ++r) {
                const float p = __shfl_xor(v[r], m, 64);
                v[r] = c * v[r] + t * p;
            }
        }
        // qubits 6-11 (register bits): must stay unrolled (static v[] indices)
        #pragma unroll
        for (int b = 0; b < 6; ++b) {
            const float c = cs[6 + b], s = sn[6 + b];
            const int M = 1 << b;
            #pragma unroll
            for (int r = 0; r < 64; ++r) {
                if (!(r & M)) {
                    const float a0 = v[r], a1 = v[r | M];
                    v[r]     = c * a0 - s * a1;
                    v[r | M] = s * a0 + c * a1;
                }
            }
        }
        // CZ ring sign (static per-r constants)
        #pragma unroll
        for (int r = 0; r < 64; ++r) {
            const int pr = __popc(r & (r >> 1) & 0x1F) & 1;
            const int r0 = r & 1, r5 = (r >> 5) & 1;
            float f = r0 ? (r5 ? f11 : f10) : (r5 ? f01 : f00);
            if (pr) f = -f;
            v[r] *= f;
        }
    }

    unsigned short* outh = pe + (size_t)smp * K_EXT;
    unsigned short* outl = outh + DIM;
    #pragma unroll
    for (int r = 0; r < 64; ++r) {
        const float x = v[r];
        const unsigned short hb = f32_to_bf16(x);
        outh[r*64 + lane] = hb;
        outl[r*64 + lane] = f32_to_bf16(x - bf16_to_f32(hb));
    }
}

// ---------------------------------------------------------------------------
// Kernel 2 (exact R6/R9 structure — known-good, no spill): bf16 Gram over
// K_EXT=8192 + fused reduction, triangular grid.  64x64 tile/block, 4 waves
// K-split within each BK=64 stage (mfma_f32_32x32x16, named acc vars),
// 2-stage NAMED-register prefetch (indexed register arrays spill ~1 GB).
// ---------------------------------------------------------------------------
__global__ __launch_bounds__(256) void gram_kernel(const unsigned short* __restrict__ pe,
                                                   const int* __restrict__ labels,
                                                   double* __restrict__ part1,
                                                   double* __restrict__ part2)
{
    __shared__ __align__(16) unsigned short stage[2*64*LDK];   // A | B, 18 KiB
    __shared__ float la[64], lb[64];

    unsigned short* A = stage;
    unsigned short* B = stage + 64*LDK;
    float*  Gt  = (float*)stage;       // alias: live after main loop (64 x 66)
    double* red = (double*)stage;      // alias: live after Gt reads complete

    const int tid = threadIdx.x;
    const int bid = blockIdx.x;

    // triangular index -> (bi,bj), bj >= bi
    int bi = (int)((65.0 - sqrt(65.0*65.0 - 8.0*(double)bid)) * 0.5);
    int start = bi*(65-bi)/2;
    while (bid < start)              { --bi; start = bi*(65-bi)/2; }
    while (bid >= start + (NT - bi)) { start += NT - bi; ++bi; }
    const int bj = bi + (bid - start);

    if (tid < 64)       la[tid]      = 2.0f*(float)labels[bi*64 + tid]      - 1.0f;
    else if (tid < 128) lb[tid - 64] = 2.0f*(float)labels[bj*64 + tid - 64] - 1.0f;

    const int wave = tid >> 6, lane = tid & 63;
    const int mrow = lane & 31;
    const int kgrp = (lane >> 5) * 8;   // A/B layout: lane holds M[lane&31][(lane>>5)*8+j]
    const int ro   = wave*16 + kgrp;    // this wave's k-offset within the stage

    floatx16 acc00, acc01, acc10, acc11;
    #pragma unroll
    for (int i = 0; i < 16; ++i) { acc00[i]=0.f; acc01[i]=0.f; acc10[i]=0.f; acc11[i]=0.f; }

    // staging map: thread -> row sr (0..63), 16B chunks at c0 and c0+32 (ushort)
    const int sr = tid >> 2;
    const int c0 = (tid & 3) * 8;
    const unsigned short* gA = pe + ((size_t)bi*64 + sr) * K_EXT + c0;
    const unsigned short* gB = pe + ((size_t)bj*64 + sr) * K_EXT + c0;
    unsigned short* sA = &A[sr*LDK + c0];
    unsigned short* sB = &B[sr*LDK + c0];

    // prologue: stage 0 -> r*, stage 1 -> s*
    uint4 ra0 = *(const uint4*)(gA +  0), ra1 = *(const uint4*)(gA + 32);
    uint4 rb0 = *(const uint4*)(gB +  0), rb1 = *(const uint4*)(gB + 32);
    uint4 sa0 = *(const uint4*)(gA + 64), sa1 = *(const uint4*)(gA + 96);
    uint4 sb0 = *(const uint4*)(gB + 64), sb1 = *(const uint4*)(gB + 96);

    for (int kk = 0; kk < K_EXT; kk += 2*BK) {
        // ---- phase A: stage kk ----
        __syncthreads();                       // prev readers done
        *(uint4*)(sA +  0) = ra0; *(uint4*)(sA + 32) = ra1;
        *(uint4*)(sB +  0) = rb0; *(uint4*)(sB + 32) = rb1;
        __syncthreads();
        if (kk + 128 < K_EXT) {                // prefetch stage kk+128
            ra0 = *(const uint4*)(gA + kk + 128); ra1 = *(const uint4*)(gA + kk + 160);
            rb0 = *(const uint4*)(gB + kk + 128); rb1 = *(const uint4*)(gB + kk + 160);
        }
        {
            const bf16x8 av0 = *(const bf16x8*)&A[(mrow     )*LDK + ro];
            const bf16x8 av1 = *(const bf16x8*)&A[(mrow + 32)*LDK + ro];
            const bf16x8 bv0 = *(const bf16x8*)&B[(mrow     )*LDK + ro];
            const bf16x8 bv1 = *(const bf16x8*)&B[(mrow + 32)*LDK + ro];
            acc00 = __builtin_amdgcn_mfma_f32_32x32x16_bf16(av0, bv0, acc00, 0, 0, 0);
            acc01 = __builtin_amdgcn_mfma_f32_32x32x16_bf16(av0, bv1, acc01, 0, 0, 0);
            acc10 = __builtin_amdgcn_mfma_f32_32x32x16_bf16(av1, bv0, acc10, 0, 0, 0);
            acc11 = __builtin_amdgcn_mfma_f32_32x32x16_bf16(av1, bv1, acc11, 0, 0, 0);
        }
        // ---- phase B: stage kk+64 ----
        __syncthreads();
        *(uint4*)(sA +  0) = sa0; *(uint4*)(sA + 32) = sa1;
        *(uint4*)(sB +  0) = sb0; *(uint4*)(sB + 32) = sb1;
        __syncthreads();
        if (kk + 192 < K_EXT) {                // prefetch stage kk+192
            sa0 = *(const uint4*)(gA + kk + 192); sa1 = *(const uint4*)(gA + kk + 224);
            sb0 = *(const uint4*)(gB + kk + 192); sb1 = *(const uint4*)(gB + kk + 224);
        }
        {
            const bf16x8 av0 = *(const bf16x8*)&A[(mrow     )*LDK + ro];
            const bf16x8 av1 = *(const bf16x8*)&A[(mrow + 32)*LDK + ro];
            const bf16x8 bv0 = *(const bf16x8*)&B[(mrow     )*LDK + ro];
            const bf16x8 bv1 = *(const bf16x8*)&B[(mrow + 32)*LDK + ro];
            acc00 = __builtin_amdgcn_mfma_f32_32x32x16_bf16(av0, bv0, acc00, 0, 0, 0);
            acc01 = __builtin_amdgcn_mfma_f32_32x32x16_bf16(av0, bv1, acc01, 0, 0, 0);
            acc10 = __builtin_amdgcn_mfma_f32_32x32x16_bf16(av1, bv0, acc10, 0, 0, 0);
            acc11 = __builtin_amdgcn_mfma_f32_32x32x16_bf16(av1, bv1, acc11, 0, 0, 0);
        }
    }

    __syncthreads();   // all staging reads done; stage memory reusable as Gt

    // Sum the 4 wave K-partials into Gt.  C/D layout (m74/m101):
    // row_local = (reg&3) + 8*(reg>>2) + 4*(lane>>5), col_local = lane&31.
    const int crow = (lane >> 5) * 4;
    const int ccol = lane & 31;
    for (int w = 0; w < 4; ++w) {
        if (wave == w) {
            #pragma unroll
            for (int r = 0; r < 16; ++r) {
                const int rl = (r & 3) + 8*(r >> 2) + crow;
                if (w == 0) {
                    Gt[(rl     )*66 + ccol     ] = acc00[r];
                    Gt[(rl     )*66 + ccol + 32] = acc01[r];
                    Gt[(rl + 32)*66 + ccol     ] = acc10[r];
                    Gt[(rl + 32)*66 + ccol + 32] = acc11[r];
                } else {
                    Gt[(rl     )*66 + ccol     ] += acc00[r];
                    Gt[(rl     )*66 + ccol + 32] += acc01[r];
                    Gt[(rl + 32)*66 + ccol     ] += acc10[r];
                    Gt[(rl + 32)*66 + ccol + 32] += acc11[r];
                }
            }
        }
        __syncthreads();
    }

    // Reduce: s1 += w*l_i*l_j*G^2, s2 += w*G^4 (w = 2 above diag, 1 on, 0 below)
    double s1 = 0.0, s2 = 0.0;
    #pragma unroll
    for (int u = 0; u < 16; ++u) {
        const int e   = u*256 + tid;
        const int row = e >> 6, col = e & 63;
        const float g = Gt[row*66 + col];
        const float w = (bi < bj) ? 2.0f : ((row < col) ? 2.0f : ((row == col) ? 1.0f : 0.0f));
        const float g2 = g * g;
        s1 += (double)(w * la[row] * lb[col] * g2);
        const double d = (double)g2;
        s2 += (double)w * d * d;
    }
    __syncthreads();   // Gt reads done before red alias is written

    red[tid] = s1; __syncthreads();
    for (int off = 128; off; off >>= 1) { if (tid < off) red[tid] += red[tid+off]; __syncthreads(); }
    if (tid == 0) part1[bid] = red[0];
    __syncthreads();
    red[tid] = s2; __syncthreads();
    for (int off = 128; off; off >>= 1) { if (tid < off) red[tid] += red[tid+off]; __syncthreads(); }
    if (tid == 0) part2[bid] = red[0];
}

// ---------------------------------------------------------------------------
// Kernel 3: reduce 528 partial slots -> scalar f32.
// square_sum_l = N^2 exactly, so out = s1 / (N * sqrt(s2)).
// ---------------------------------------------------------------------------
__global__ __launch_bounds__(256) void finalize_kernel(const double* __restrict__ part1,
                                                       const double* __restrict__ part2,
                                                       float* __restrict__ out)
{
    __shared__ double r1[256], r2[256];
    const int tid = threadIdx.x;
    double a = 0.0, b = 0.0;
    #pragma unroll
    for (int u = 0; u < 3; ++u) {
        const int s = tid + u*256;
        if (s < NTRI) { a += part1[s]; b += part2[s]; }
    }
    r1[tid] = a; r2[tid] = b; __syncthreads();
    for (int off = 128; off; off >>= 1) {
        if (tid < off) { r1[tid] += r1[tid+off]; r2[tid] += r2[tid+off]; }
        __syncthreads();
    }
    if (tid == 0) out[0] = (float)(r1[0] / (sqrt(r2[0]) * (double)NSAMP));
}

// ---------------------------------------------------------------------------
extern "C" void kernel_launch(void* const* d_in, const int* in_sizes, int n_in,
                              void* d_out, int out_size, void* d_ws, size_t ws_size,
                              hipStream_t stream)
{
    const float* data   = (const float*)d_in[0]; // (2048,12) f32
    const int*   labels = (const int*)d_in[1];   // (2048,)   i32
    const float* params = (const float*)d_in[2]; // (3,12)    f32

    double* part1 = (double*)d_ws;                                    // 528 doubles
    double* part2 = part1 + NTRI;                                     // 528 doubles
    unsigned short* psi_ext = (unsigned short*)((char*)d_ws + 16384); // 2048x8192 bf16 = 32 MiB

    sim_kernel<<<NSAMP/4, 256, 0, stream>>>(data, params, psi_ext);
    gram_kernel<<<NTRI, 256, 0, stream>>>(psi_ext, labels, part1, part2);
    finalize_kernel<<<1, 256, 0, stream>>>(part1, part2, (float*)d_out);
}